// Round 1
// baseline (623.764 us; speedup 1.0000x reference)
//
#include <hip/hip_runtime.h>
#include <hip/hip_bf16.h>
#include <math.h>

#define EMB_DIM 4096
#define INNER   1024
#define VOCAB   32000
#define NPRED   3
#define SEQ     512
#define TOKENS  1024   // B*N = 2*512

typedef __attribute__((ext_vector_type(8))) short bf16x8;
typedef __attribute__((ext_vector_type(4))) float f32x4;

__device__ inline void gload_lds16(const void* g, void* l) {
  __builtin_amdgcn_global_load_lds(
      (const __attribute__((address_space(1))) void*)g,
      (__attribute__((address_space(3))) void*)l, 16, 0, 0);
}

__device__ inline unsigned short f2bf(float f) {
  unsigned u = __float_as_uint(f);
  u += 0x7fffu + ((u >> 16) & 1u);
  return (unsigned short)(u >> 16);
}

// ---------------- f32 -> bf16 convert, x4 vectorized ----------------
__global__ void cvt_kernel(const float4* __restrict__ in, ushort4* __restrict__ out, int n4) {
  int stride = gridDim.x * blockDim.x;
  for (int i = blockIdx.x * blockDim.x + threadIdx.x; i < n4; i += stride) {
    float4 v = in[i];
    ushort4 o;
    o.x = f2bf(v.x); o.y = f2bf(v.y); o.z = f2bf(v.z); o.w = f2bf(v.w);
    out[i] = o;
  }
}

// ---------------- GEMM: C[M][N] = A[M][K] * B[N][K]^T (bf16 in, f32 out) ----
// 128x128 tile, BK=32, 4 waves (2x2), each wave 64x64 = 4x4 frags of 16x16.
__global__ __launch_bounds__(256) void gemm_bt(const __hip_bfloat16* __restrict__ A,
                                               const __hip_bfloat16* __restrict__ B,
                                               float* __restrict__ C,
                                               int M, int N, int K) {
  __shared__ char smem[16384];
  char* As = smem;          // [128][32] bf16 = 8192 B
  char* Bs = smem + 8192;   // [128][32] bf16

  const int tid  = threadIdx.x;
  const int lane = tid & 63;
  const int wave = tid >> 6;
  const int wm = wave >> 1, wn = wave & 1;

  const int bm = blockIdx.y * 128;
  const int bn = blockIdx.x * 128;

  // staging: thread t covers row t>>2 (and +64), 8 bf16 at k-offset (t&3)*8
  const char* Ag = (const char*)(A + (size_t)(bm + (tid >> 2)) * K + (tid & 3) * 8);
  const char* Bg = (const char*)(B + (size_t)(bn + (tid >> 2)) * K + (tid & 3) * 8);
  const size_t rowskip = (size_t)64 * K * 2;  // 64 rows, bytes

  f32x4 acc[4][4] = {};

  // LDS fragment byte offsets: row = (wm*64 + frag*16 + (lane&15)), kbyte = (lane>>4)*16
  const int fa = (wm * 64 + (lane & 15)) * 64 + (lane >> 4) * 16;
  const int fb = (wn * 64 + (lane & 15)) * 64 + (lane >> 4) * 16;

  for (int k0 = 0; k0 < K; k0 += 32) {
    gload_lds16(Ag,           As + tid * 16);
    gload_lds16(Ag + rowskip, As + 4096 + tid * 16);
    gload_lds16(Bg,           Bs + tid * 16);
    gload_lds16(Bg + rowskip, Bs + 4096 + tid * 16);
    Ag += 64; Bg += 64;  // advance 32 bf16 along k
    __syncthreads();

    bf16x8 af[4], bfv[4];
#pragma unroll
    for (int m = 0; m < 4; ++m) af[m]  = *(const bf16x8*)(As + fa + m * 1024);
#pragma unroll
    for (int n = 0; n < 4; ++n) bfv[n] = *(const bf16x8*)(Bs + fb + n * 1024);
#pragma unroll
    for (int m = 0; m < 4; ++m)
#pragma unroll
      for (int n = 0; n < 4; ++n)
        acc[m][n] = __builtin_amdgcn_mfma_f32_16x16x32_bf16(af[m], bfv[n], acc[m][n], 0, 0, 0);
    __syncthreads();
  }

  // epilogue: C/D layout col = lane&15, row = (lane>>4)*4 + r
  const int r0 = bm + wm * 64 + (lane >> 4) * 4;
  const int c0 = bn + wn * 64 + (lane & 15);
#pragma unroll
  for (int m = 0; m < 4; ++m)
#pragma unroll
    for (int n = 0; n < 4; ++n) {
      float* Cp = C + (size_t)(r0 + m * 16) * N + (c0 + n * 16);
#pragma unroll
      for (int r = 0; r < 4; ++r)
        Cp[(size_t)r * N] = acc[m][n][r];
    }
}

// ---------------- fused: s = ns + alpha*z ; RMS-LN ; exact GELU ; -> bf16 ----
__global__ __launch_bounds__(256) void fuse_ln_gelu(const float* __restrict__ ns,
    const float* __restrict__ emb,   // emb_w[i] base: [VOCAB][INNER]
    const int* __restrict__ inds,    // [2][SEQ+NPRED]
    const float* __restrict__ lnw, const float* __restrict__ lnb,
    ushort4* __restrict__ out_bf16,  // [TOKENS][INNER] bf16
    int i, float alpha)
{
  const int t = blockIdx.x;          // token 0..1023
  const int b = t >> 9, n = t & 511;
  const int idx = inds[b * (SEQ + NPRED) + n + i];

  const float4* x = (const float4*)(ns + (size_t)t * INNER);
  const float4* z = (const float4*)(emb + (size_t)idx * INNER);
  const int j = threadIdx.x;         // each thread: 4 elems

  float4 xv = x[j], zv = z[j];
  float4 v;
  v.x = xv.x + alpha * zv.x;
  v.y = xv.y + alpha * zv.y;
  v.z = xv.z + alpha * zv.z;
  v.w = xv.w + alpha * zv.w;

  float ss = v.x * v.x + v.y * v.y + v.z * v.z + v.w * v.w;
#pragma unroll
  for (int o = 32; o > 0; o >>= 1) ss += __shfl_down(ss, o);
  __shared__ float red[4];
  if ((threadIdx.x & 63) == 0) red[threadIdx.x >> 6] = ss;
  __syncthreads();
  float total = red[0] + red[1] + red[2] + red[3];
  float r = rsqrtf(total * (1.0f / INNER) + 1e-6f);

  float4 wv = ((const float4*)lnw)[j];
  float4 bv = ((const float4*)lnb)[j];
  const float inv_sqrt2 = 0.70710678118654752f;
  ushort4 o;
  float y;
  y = v.x * r * wv.x + bv.x; o.x = f2bf(0.5f * y * (1.0f + erff(y * inv_sqrt2)));
  y = v.y * r * wv.y + bv.y; o.y = f2bf(0.5f * y * (1.0f + erff(y * inv_sqrt2)));
  y = v.z * r * wv.z + bv.z; o.z = f2bf(0.5f * y * (1.0f + erff(y * inv_sqrt2)));
  y = v.w * r * wv.w + bv.w; o.w = f2bf(0.5f * y * (1.0f + erff(y * inv_sqrt2)));

  out_bf16[(size_t)t * (INNER / 4) + j] = o;
}

extern "C" void kernel_launch(void* const* d_in, const int* in_sizes, int n_in,
                              void* d_out, int out_size, void* d_ws, size_t ws_size,
                              hipStream_t stream) {
  const float* state = (const float*)d_in[0];
  const int*   inds  = (const int*)d_in[1];
  const float* emb_w = (const float*)d_in[2];
  const float* proj0 = (const float*)d_in[3];
  const float* projw = (const float*)d_in[4];
  const float* headw = (const float*)d_in[5];
  const float* lnw   = (const float*)d_in[6];
  const float* lnb   = (const float*)d_in[7];
  float* out = (float*)d_out;

  char* ws = (char*)d_ws;
  __hip_bfloat16* stateA = (__hip_bfloat16*)(ws);                    // 1024*4096 bf16  = 8,388,608
  __hip_bfloat16* stateI = (__hip_bfloat16*)(ws + 8388608);          // 1024*1024 bf16  = 2,097,152
  float*          nsf    = (float*)        (ws + 10485760);          // 1024*1024 f32   = 4,194,304
  __hip_bfloat16* p0b    = (__hip_bfloat16*)(ws + 14680064);         // 1024*4096 bf16  = 8,388,608
  __hip_bfloat16* pwb    = (__hip_bfloat16*)(ws + 23068672);         // 2*1024*1024 bf16= 4,194,304
  __hip_bfloat16* hb     = (__hip_bfloat16*)(ws + 27262976);         // 32000*1024 bf16 = 65,536,000
  // total ws use: 92,798,976 bytes

  double sw = pow(0.5, 1.0 / 6.0);
  float alpha = (float)(sqrt((1.0 - sw * sw) * (INNER / 2.0)) / sw);

  auto cvt = [&](const float* src, __hip_bfloat16* dst, size_t n) {
    int n4 = (int)(n / 4);
    int blocks = (n4 + 255) / 256;
    if (blocks > 4096) blocks = 4096;
    cvt_kernel<<<dim3(blocks), dim3(256), 0, stream>>>((const float4*)src, (ushort4*)dst, n4);
  };

  cvt(state, stateA, (size_t)TOKENS * EMB_DIM);
  cvt(proj0, p0b, (size_t)INNER * EMB_DIM);
  cvt(projw, pwb, (size_t)2 * INNER * INNER);

  for (int i = 0; i < NPRED; ++i) {
    cvt(headw + (size_t)i * VOCAB * INNER, hb, (size_t)VOCAB * INNER);

    const __hip_bfloat16* Ab = (i == 0) ? stateA : stateI;
    const __hip_bfloat16* Bb = (i == 0) ? p0b : pwb + (size_t)(i - 1) * INNER * INNER;
    int K = (i == 0) ? EMB_DIM : INNER;
    gemm_bt<<<dim3(INNER / 128, TOKENS / 128), dim3(256), 0, stream>>>(Ab, Bb, nsf, TOKENS, INNER, K);

    fuse_ln_gelu<<<dim3(TOKENS), dim3(256), 0, stream>>>(nsf,
        emb_w + (size_t)i * VOCAB * INNER, inds,
        lnw + i * INNER, lnb + i * INNER, (ushort4*)stateI, i, alpha);

    gemm_bt<<<dim3(VOCAB / 128, TOKENS / 128), dim3(256), 0, stream>>>(stateI, hb,
        out + (size_t)i * TOKENS * VOCAB, TOKENS, VOCAB, INNER);
  }
}